// Round 4
// baseline (940.362 us; speedup 1.0000x reference)
//
#include <hip/hip_runtime.h>
#include <hip/hip_bf16.h>
#include <stdint.h>

// Problem constants (B=2, S=2048, D=1024, E=8, F=2048, K=2)
// Inputs/outputs are FLOAT32 (per reference). Internal compute: bf16 MFMA.
#define D_MODEL 1024
#define NEXP 8
#define FF 2048
#define TOPK 2
#define NTOK 4096                       // B*S tokens
#define MT 128                          // M-tile (rows)
#define BK 64                           // K-tile
#define MAXROWS (NTOK*TOPK + NEXP*MT)   // 9216 (worst-case padded rows)
#define MAXTILES (MAXROWS/MT)           // 72

typedef __bf16 bf16x8 __attribute__((ext_vector_type(8)));
typedef float f32x4 __attribute__((ext_vector_type(4)));

__device__ inline unsigned short f2b(float f){
  __hip_bfloat16 h = __float2bfloat16(f);
  return __builtin_bit_cast(unsigned short, h);
}

// ---------------- fallback: zero output (diagnostic path if ws too small) ----
__global__ void zero_out_kernel(float* out, int n){
  int i = blockIdx.x*256 + threadIdx.x;
  if (i < n) out[i] = 0.f;
}

// ---------------- fp32 -> bf16 conversion (vectorized) ----------------
__global__ __launch_bounds__(256) void conv_kernel(
    const float* __restrict__ in, unsigned short* __restrict__ out, long n4)
{
  long i = (long)blockIdx.x*256 + threadIdx.x;
  if (i >= n4) return;
  float4 v = reinterpret_cast<const float4*>(in)[i];
  ushort4 o;
  o.x = f2b(v.x); o.y = f2b(v.y); o.z = f2b(v.z); o.w = f2b(v.w);
  reinterpret_cast<ushort4*>(out)[i] = o;
}

// ---------------- bookkeeping kernels ----------------

__global__ void init_kernel(int* perm, int* ctrl){
  int i = blockIdx.x*256 + threadIdx.x;
  if (i < MAXROWS) perm[i] = -1;
  if (i < 64) ctrl[i] = 0;
}

// One wave per token: logits (8 dots of length 1024) in fp32, softmax, top-2,
// L1-renorm. Reference casts renormed weights to x.dtype = fp32 (no rounding).
__global__ __launch_bounds__(256) void router_kernel(
    const float* __restrict__ x, const float* __restrict__ rw,
    float* __restrict__ topw, int* __restrict__ tope, int* __restrict__ counts)
{
  const int wid = threadIdx.x >> 6, lane = threadIdx.x & 63;
  const int t = blockIdx.x*4 + wid;
  float p[NEXP];
  #pragma unroll
  for (int e=0;e<NEXP;e++) p[e] = 0.f;
  for (int i=0;i<16;i++){
    int d = i*64 + lane;
    float xv = x[(long)t*D_MODEL + d];
    #pragma unroll
    for (int e=0;e<NEXP;e++) p[e] += xv * rw[e*D_MODEL + d];
  }
  #pragma unroll
  for (int e=0;e<NEXP;e++)
    for (int off=32; off; off>>=1) p[e] += __shfl_xor(p[e], off, 64);
  if (lane == 0){
    float mx = p[0];
    #pragma unroll
    for (int e=1;e<NEXP;e++) mx = fmaxf(mx, p[e]);
    float w[NEXP]; float s = 0.f;
    #pragma unroll
    for (int e=0;e<NEXP;e++){ w[e] = expf(p[e]-mx); s += w[e]; }
    #pragma unroll
    for (int e=0;e<NEXP;e++) w[e] /= s;
    int e1 = 0;
    #pragma unroll
    for (int e=1;e<NEXP;e++) if (w[e] > w[e1]) e1 = e;   // ties -> lowest idx (jax top_k)
    int e2 = -1;
    #pragma unroll
    for (int e=0;e<NEXP;e++) if (e != e1 && (e2 < 0 || w[e] > w[e2])) e2 = e;
    float s2 = w[e1] + w[e2];
    topw[t*2+0] = w[e1]/s2;
    topw[t*2+1] = w[e2]/s2;
    tope[t*2+0] = e1; tope[t*2+1] = e2;
    atomicAdd(&counts[e1], 1); atomicAdd(&counts[e2], 1);
  }
}

__global__ void partition_kernel(const int* ctrl, int* segStart, int* tileExpert){
  if (threadIdx.x == 0 && blockIdx.x == 0){
    int off = 0, tile = 0;
    for (int e=0;e<NEXP;e++){
      segStart[e] = off;
      int padded = ((ctrl[e] + MT - 1)/MT)*MT;
      off += padded;
      for (int k=0;k<padded/MT && tile < MAXTILES;k++) tileExpert[tile++] = e;
    }
    segStart[NEXP] = off;
    while (tile < MAXTILES) tileExpert[tile++] = -1;
  }
}

__global__ void scatter_kernel(const int* tope, const int* segStart, int* fill,
                               int* perm, int* rowOf){
  int i = blockIdx.x*256 + threadIdx.x;           // (token,k) pair index, 0..8191
  int e = tope[i];
  int pos = segStart[e] + atomicAdd(&fill[e], 1);
  if (pos >= 0 && pos < MAXROWS){ perm[pos] = i >> 1; rowOf[i] = pos; }
}

// w2 (E,F,D) fp32 -> w2t (E,D,F) bf16: transpose + convert fused
__global__ void transpose_w2(const float* __restrict__ w2,
                             unsigned short* __restrict__ w2t){
  __shared__ unsigned short tl[32][33];
  const int e = blockIdx.z;
  const int d0 = blockIdx.x*32, f0 = blockIdx.y*32;
  const int tx = threadIdx.x, ty = threadIdx.y;
  #pragma unroll
  for (int i=0;i<4;i++)
    tl[ty + i*8][tx] = f2b(w2[((long)(e*FF + f0 + ty + i*8))*D_MODEL + d0 + tx]);
  __syncthreads();
  #pragma unroll
  for (int i=0;i<4;i++)
    w2t[((long)e*D_MODEL + d0 + ty + i*8)*FF + f0 + tx] = tl[tx][ty + i*8];
}

// ---------------- GEMM1: Hg = silu(Xg @ w1e^T) * (Xg @ v1e^T) ----------------
// All operands pre-converted bf16. Explicit uint4 staging, XOR-swizzled LDS.
__global__ __launch_bounds__(256, 2) void gemm1_swiglu(
    const unsigned short* __restrict__ x,
    const unsigned short* __restrict__ w1,
    const unsigned short* __restrict__ v1,
    const int* __restrict__ perm,
    const int* __restrict__ tileExpert,
    unsigned short* __restrict__ Hg)
{
  const int mt = blockIdx.x, nt = blockIdx.y;
  int e = tileExpert[mt];
  if (e < 0) return;
  e &= 7;
  __shared__ alignas(16) unsigned short As [MT*BK];
  __shared__ alignas(16) unsigned short B1s[MT*BK];
  __shared__ alignas(16) unsigned short B2s[MT*BK];
  const int tid = threadIdx.x;
  const int lane = tid & 63;
  const int wr = ((tid >> 7) & 1) * 64;
  const int wc = ((tid >> 6) & 1) * 64;

  long aoff[4]; long boff[4]; int dstIdx[4];
  #pragma unroll
  for (int i=0;i<4;i++){
    int idx = tid + 256*i;
    int r = idx >> 3, c = idx & 7;
    int sc = c ^ (r & 7);                 // XOR swizzle (applied on global side)
    int tok = perm[mt*MT + r]; if (tok < 0 || tok >= NTOK) tok = 0;
    aoff[i] = (long)tok * D_MODEL + sc*8;
    boff[i] = ((long)e*FF + nt*MT + r) * D_MODEL + sc*8;
    dstIdx[i] = idx * 8;
  }
  f32x4 zero = {0.f,0.f,0.f,0.f};
  f32x4 acc1[4][4], acc2[4][4];
  #pragma unroll
  for (int i=0;i<4;i++)
    #pragma unroll
    for (int j=0;j<4;j++){ acc1[i][j] = zero; acc2[i][j] = zero; }

  for (int k0 = 0; k0 < D_MODEL; k0 += BK){
    uint4 ta[4], tb1[4], tb2[4];
    #pragma unroll
    for (int i=0;i<4;i++){
      ta [i] = *reinterpret_cast<const uint4*>(x  + aoff[i] + k0);
      tb1[i] = *reinterpret_cast<const uint4*>(w1 + boff[i] + k0);
      tb2[i] = *reinterpret_cast<const uint4*>(v1 + boff[i] + k0);
    }
    __syncthreads();
    #pragma unroll
    for (int i=0;i<4;i++){
      *reinterpret_cast<uint4*>(&As [dstIdx[i]]) = ta [i];
      *reinterpret_cast<uint4*>(&B1s[dstIdx[i]]) = tb1[i];
      *reinterpret_cast<uint4*>(&B2s[dstIdx[i]]) = tb2[i];
    }
    __syncthreads();
    #pragma unroll
    for (int kk = 0; kk < BK; kk += 32){
      const int q = (lane >> 4) + (kk >> 3);   // logical 8-elem chunk 0..7
      bf16x8 a[4], bb1[4], bb2[4];
      #pragma unroll
      for (int i=0;i<4;i++){
        int r = wr + i*16 + (lane & 15);
        a[i] = *reinterpret_cast<const bf16x8*>(&As[r*BK + ((q ^ (r&7))*8)]);
      }
      #pragma unroll
      for (int j=0;j<4;j++){
        int n = wc + j*16 + (lane & 15);
        int adr = n*BK + ((q ^ (n&7))*8);
        bb1[j] = *reinterpret_cast<const bf16x8*>(&B1s[adr]);
        bb2[j] = *reinterpret_cast<const bf16x8*>(&B2s[adr]);
      }
      #pragma unroll
      for (int i=0;i<4;i++)
        #pragma unroll
        for (int j=0;j<4;j++){
          acc1[i][j] = __builtin_amdgcn_mfma_f32_16x16x32_bf16(a[i], bb1[j], acc1[i][j], 0,0,0);
          acc2[i][j] = __builtin_amdgcn_mfma_f32_16x16x32_bf16(a[i], bb2[j], acc2[i][j], 0,0,0);
        }
    }
  }
  // epilogue: h = silu(g)*u, write bf16.  C/D layout: col=lane&15, row=quad*4+reg
  const int mrow0 = mt*MT + wr + ((lane >> 4) << 2);
  const int ncol0 = nt*MT + wc + (lane & 15);
  #pragma unroll
  for (int i=0;i<4;i++)
    #pragma unroll
    for (int j=0;j<4;j++)
      #pragma unroll
      for (int rr=0;rr<4;rr++){
        float g = acc1[i][j][rr];
        float u = acc2[i][j][rr];
        float h = (g / (1.0f + __expf(-g))) * u;
        Hg[(long)(mrow0 + i*16 + rr)*FF + (ncol0 + j*16)] = f2b(h);
      }
}

// ---------------- GEMM2: Yg(fp32) = Hg @ w2e  (B from transposed w2t) --------
__global__ __launch_bounds__(256, 2) void gemm2_kernel(
    const unsigned short* __restrict__ Hg,
    const unsigned short* __restrict__ w2t,   // [E][D][F] bf16
    const int* __restrict__ tileExpert,
    float* __restrict__ Yg)
{
  const int mt = blockIdx.x, nt = blockIdx.y;
  int e = tileExpert[mt];
  if (e < 0) return;
  e &= 7;
  __shared__ alignas(16) unsigned short As[MT*BK];
  __shared__ alignas(16) unsigned short Bs[MT*BK];
  const int tid = threadIdx.x;
  const int lane = tid & 63;
  const int wr = ((tid >> 7) & 1) * 64;
  const int wc = ((tid >> 6) & 1) * 64;

  long aoff[4]; long boff[4]; int dstIdx[4];
  #pragma unroll
  for (int i=0;i<4;i++){
    int idx = tid + 256*i;
    int r = idx >> 3, c = idx & 7;
    int sc = c ^ (r & 7);
    aoff[i] = (long)(mt*MT + r) * FF + sc*8;
    boff[i] = ((long)e*D_MODEL + nt*MT + r) * FF + sc*8;
    dstIdx[i] = idx * 8;
  }
  f32x4 zero = {0.f,0.f,0.f,0.f};
  f32x4 acc[4][4];
  #pragma unroll
  for (int i=0;i<4;i++)
    #pragma unroll
    for (int j=0;j<4;j++) acc[i][j] = zero;

  for (int k0 = 0; k0 < FF; k0 += BK){
    uint4 ta[4], tb[4];
    #pragma unroll
    for (int i=0;i<4;i++){
      ta[i] = *reinterpret_cast<const uint4*>(Hg  + aoff[i] + k0);
      tb[i] = *reinterpret_cast<const uint4*>(w2t + boff[i] + k0);
    }
    __syncthreads();
    #pragma unroll
    for (int i=0;i<4;i++){
      *reinterpret_cast<uint4*>(&As[dstIdx[i]]) = ta[i];
      *reinterpret_cast<uint4*>(&Bs[dstIdx[i]]) = tb[i];
    }
    __syncthreads();
    #pragma unroll
    for (int kk = 0; kk < BK; kk += 32){
      const int q = (lane >> 4) + (kk >> 3);
      bf16x8 a[4], bb[4];
      #pragma unroll
      for (int i=0;i<4;i++){
        int r = wr + i*16 + (lane & 15);
        a[i] = *reinterpret_cast<const bf16x8*>(&As[r*BK + ((q ^ (r&7))*8)]);
      }
      #pragma unroll
      for (int j=0;j<4;j++){
        int n = wc + j*16 + (lane & 15);
        bb[j] = *reinterpret_cast<const bf16x8*>(&Bs[n*BK + ((q ^ (n&7))*8)]);
      }
      #pragma unroll
      for (int i=0;i<4;i++)
        #pragma unroll
        for (int j=0;j<4;j++)
          acc[i][j] = __builtin_amdgcn_mfma_f32_16x16x32_bf16(a[i], bb[j], acc[i][j], 0,0,0);
    }
  }
  const int mrow0 = mt*MT + wr + ((lane >> 4) << 2);
  const int ncol0 = nt*MT + wc + (lane & 15);
  #pragma unroll
  for (int i=0;i<4;i++)
    #pragma unroll
    for (int j=0;j<4;j++)
      #pragma unroll
      for (int rr=0;rr<4;rr++)
        Yg[(long)(mrow0 + i*16 + rr)*D_MODEL + (ncol0 + j*16)] = acc[i][j][rr];
}

// ---------------- combine: out[t] = w0*Yg[r0] + w1*Yg[r1]  (fp32) ------------
__global__ __launch_bounds__(256) void combine_kernel(
    const float* __restrict__ Yg, const float* __restrict__ topw,
    const int* __restrict__ rowOf, float* __restrict__ out)
{
  const int t = blockIdx.x;
  const int d = threadIdx.x * 4;
  const float wA = topw[2*t], wB = topw[2*t+1];
  long rA = rowOf[2*t], rB = rowOf[2*t+1];
  if (rA < 0 || rA >= MAXROWS) rA = 0;
  if (rB < 0 || rB >= MAXROWS) rB = 0;
  float4 a = *reinterpret_cast<const float4*>(Yg + rA*D_MODEL + d);
  float4 b = *reinterpret_cast<const float4*>(Yg + rB*D_MODEL + d);
  float4 o;
  o.x = wA*a.x + wB*b.x;
  o.y = wA*a.y + wB*b.y;
  o.z = wA*a.z + wB*b.z;
  o.w = wA*a.w + wB*b.w;
  *reinterpret_cast<float4*>(out + (long)t*D_MODEL + d) = o;
}

// ---------------- launch ----------------
extern "C" void kernel_launch(void* const* d_in, const int* in_sizes, int n_in,
                              void* d_out, int out_size, void* d_ws, size_t ws_size,
                              hipStream_t stream)
{
  const float* x  = (const float*)d_in[0];
  const float* w1 = (const float*)d_in[1];
  const float* v1 = (const float*)d_in[2];
  const float* w2 = (const float*)d_in[3];
  const float* rw = (const float*)d_in[4];
  float* out = (float*)d_out;
  (void)in_sizes; (void)n_in;

  // --- workspace layout + budget check ---
  size_t need = 0;
  auto count = [&](size_t b){ size_t r = need; need += (b + 255) & ~(size_t)255; return r; };
  size_t o_topw = count((size_t)NTOK*TOPK*sizeof(float));
  size_t o_tope = count((size_t)NTOK*TOPK*sizeof(int));
  size_t o_ctrl = count(64*sizeof(int));
  size_t o_seg  = count(16*sizeof(int));
  size_t o_te   = count(MAXTILES*sizeof(int));
  size_t o_perm = count(MAXROWS*sizeof(int));
  size_t o_rowOf= count((size_t)NTOK*TOPK*sizeof(int));
  size_t o_xb   = count((size_t)NTOK*D_MODEL*2);          // bf16 x
  size_t o_w1b  = count((size_t)NEXP*FF*D_MODEL*2);       // bf16 w1
  size_t o_v1b  = count((size_t)NEXP*FF*D_MODEL*2);       // bf16 v1
  size_t o_w2t  = count((size_t)NEXP*D_MODEL*FF*2);       // bf16 w2^T
  size_t o_Hg   = count((size_t)MAXROWS*FF*2);            // bf16 hidden
  size_t o_Yg   = count((size_t)MAXROWS*D_MODEL*sizeof(float)); // fp32 expert out

  if (ws_size < need){
    // diagnostic fallback: clean wrong-answer (absmax=max|ref|) instead of fault
    zero_out_kernel<<<(out_size+255)/256, 256, 0, stream>>>(out, out_size);
    return;
  }

  char* base = (char*)d_ws;
  float* topw      = (float*)(base + o_topw);
  int*   tope      = (int*)  (base + o_tope);
  int*   ctrl      = (int*)  (base + o_ctrl);   // counts=ctrl[0..7], fill=ctrl[8..15]
  int*   segStart  = (int*)  (base + o_seg);
  int*   tileExpert= (int*)  (base + o_te);
  int*   perm      = (int*)  (base + o_perm);
  int*   rowOf     = (int*)  (base + o_rowOf);
  unsigned short* xb  = (unsigned short*)(base + o_xb);
  unsigned short* w1b = (unsigned short*)(base + o_w1b);
  unsigned short* v1b = (unsigned short*)(base + o_v1b);
  unsigned short* w2t = (unsigned short*)(base + o_w2t);
  unsigned short* Hg  = (unsigned short*)(base + o_Hg);
  float*          Yg  = (float*)         (base + o_Yg);

  const long nx4 = (long)NTOK*D_MODEL/4;        // 1M float4s
  const long nw4 = (long)NEXP*FF*D_MODEL/4;     // 4M float4s

  init_kernel     <<<(MAXROWS+255)/256, 256, 0, stream>>>(perm, ctrl);
  router_kernel   <<<NTOK/4, 256, 0, stream>>>(x, rw, topw, tope, ctrl);
  partition_kernel<<<1, 64, 0, stream>>>(ctrl, segStart, tileExpert);
  scatter_kernel  <<<NTOK*TOPK/256, 256, 0, stream>>>(tope, segStart, ctrl+8, perm, rowOf);
  conv_kernel     <<<(nx4+255)/256, 256, 0, stream>>>(x,  xb,  nx4);
  conv_kernel     <<<(nw4+255)/256, 256, 0, stream>>>(w1, w1b, nw4);
  conv_kernel     <<<(nw4+255)/256, 256, 0, stream>>>(v1, v1b, nw4);
  transpose_w2    <<<dim3(D_MODEL/32, FF/32, NEXP), dim3(32,8), 0, stream>>>(w2, w2t);
  gemm1_swiglu    <<<dim3(MAXTILES, FF/MT), 256, 0, stream>>>(xb, w1b, v1b, perm, tileExpert, Hg);
  gemm2_kernel    <<<dim3(MAXTILES, D_MODEL/MT), 256, 0, stream>>>(Hg, w2t, tileExpert, Yg);
  combine_kernel  <<<NTOK, 256, 0, stream>>>(Yg, topw, rowOf, out);
}

// Round 5
// 634.037 us; speedup vs baseline: 1.4831x; 1.4831x over previous
//
#include <hip/hip_runtime.h>
#include <hip/hip_bf16.h>
#include <stdint.h>

// Problem constants (B=2, S=2048, D=1024, E=8, F=2048, K=2)
// Inputs/outputs are FLOAT32 (per reference). Internal compute: bf16 MFMA.
#define D_MODEL 1024
#define NEXP 8
#define FF 2048
#define TOPK 2
#define NTOK 4096                       // B*S tokens
#define MT 128                          // M-tile (rows)
#define BK 64                           // K-tile
#define MAXROWS (NTOK*TOPK + NEXP*MT)   // 9216 (worst-case padded rows)
#define MAXTILES (MAXROWS/MT)           // 72 = 8 XCDs * 9 stripes

typedef __bf16 bf16x8 __attribute__((ext_vector_type(8)));
typedef float f32x4 __attribute__((ext_vector_type(4)));

__device__ inline unsigned short f2b(float f){
  __hip_bfloat16 h = __float2bfloat16(f);
  return __builtin_bit_cast(unsigned short, h);
}

// async global->LDS, 16B per lane; LDS dst is wave-uniform base + lane*16
__device__ inline void gl2lds16(const unsigned short* g, unsigned short* l){
  __builtin_amdgcn_global_load_lds(
      (const __attribute__((address_space(1))) unsigned int*)g,
      (__attribute__((address_space(3))) unsigned int*)l, 16, 0, 0);
}

// ---------------- fallback: zero output (diagnostic path if ws too small) ----
__global__ void zero_out_kernel(float* out, int n){
  int i = blockIdx.x*256 + threadIdx.x;
  if (i < n) out[i] = 0.f;
}

// ---------------- fp32 -> bf16 conversion (vectorized) ----------------
__global__ __launch_bounds__(256) void conv_kernel(
    const float* __restrict__ in, unsigned short* __restrict__ out, long n4)
{
  long i = (long)blockIdx.x*256 + threadIdx.x;
  if (i >= n4) return;
  float4 v = reinterpret_cast<const float4*>(in)[i];
  ushort4 o;
  o.x = f2b(v.x); o.y = f2b(v.y); o.z = f2b(v.z); o.w = f2b(v.w);
  reinterpret_cast<ushort4*>(out)[i] = o;
}

// ---------------- bookkeeping kernels ----------------

__global__ void init_kernel(int* perm, int* ctrl){
  int i = blockIdx.x*256 + threadIdx.x;
  if (i < MAXROWS) perm[i] = -1;
  if (i < 64) ctrl[i] = 0;
}

// One wave per token: logits (8 dots of length 1024) in fp32, softmax, top-2,
// L1-renorm. Reference casts renormed weights to x.dtype = fp32 (no rounding).
__global__ __launch_bounds__(256) void router_kernel(
    const float* __restrict__ x, const float* __restrict__ rw,
    float* __restrict__ topw, int* __restrict__ tope, int* __restrict__ counts)
{
  const int wid = threadIdx.x >> 6, lane = threadIdx.x & 63;
  const int t = blockIdx.x*4 + wid;
  float p[NEXP];
  #pragma unroll
  for (int e=0;e<NEXP;e++) p[e] = 0.f;
  for (int i=0;i<16;i++){
    int d = i*64 + lane;
    float xv = x[(long)t*D_MODEL + d];
    #pragma unroll
    for (int e=0;e<NEXP;e++) p[e] += xv * rw[e*D_MODEL + d];
  }
  #pragma unroll
  for (int e=0;e<NEXP;e++)
    for (int off=32; off; off>>=1) p[e] += __shfl_xor(p[e], off, 64);
  if (lane == 0){
    float mx = p[0];
    #pragma unroll
    for (int e=1;e<NEXP;e++) mx = fmaxf(mx, p[e]);
    float w[NEXP]; float s = 0.f;
    #pragma unroll
    for (int e=0;e<NEXP;e++){ w[e] = expf(p[e]-mx); s += w[e]; }
    #pragma unroll
    for (int e=0;e<NEXP;e++) w[e] /= s;
    int e1 = 0;
    #pragma unroll
    for (int e=1;e<NEXP;e++) if (w[e] > w[e1]) e1 = e;   // ties -> lowest idx (jax top_k)
    int e2 = -1;
    #pragma unroll
    for (int e=0;e<NEXP;e++) if (e != e1 && (e2 < 0 || w[e] > w[e2])) e2 = e;
    float s2 = w[e1] + w[e2];
    topw[t*2+0] = w[e1]/s2;
    topw[t*2+1] = w[e2]/s2;
    tope[t*2+0] = e1; tope[t*2+1] = e2;
    atomicAdd(&counts[e1], 1); atomicAdd(&counts[e2], 1);
  }
}

__global__ void partition_kernel(const int* ctrl, int* segStart, int* tileExpert){
  if (threadIdx.x == 0 && blockIdx.x == 0){
    int off = 0, tile = 0;
    for (int e=0;e<NEXP;e++){
      segStart[e] = off;
      int padded = ((ctrl[e] + MT - 1)/MT)*MT;
      off += padded;
      for (int k=0;k<padded/MT && tile < MAXTILES;k++) tileExpert[tile++] = e;
    }
    segStart[NEXP] = off;
    while (tile < MAXTILES) tileExpert[tile++] = -1;
  }
}

__global__ void scatter_kernel(const int* tope, const int* segStart, int* fill,
                               int* perm, int* rowOf){
  int i = blockIdx.x*256 + threadIdx.x;           // (token,k) pair index, 0..8191
  int e = tope[i];
  int pos = segStart[e] + atomicAdd(&fill[e], 1);
  if (pos >= 0 && pos < MAXROWS){ perm[pos] = i >> 1; rowOf[i] = pos; }
}

// w2 (E,F,D) fp32 -> w2t (E,D,F) bf16: transpose + convert fused
__global__ void transpose_w2(const float* __restrict__ w2,
                             unsigned short* __restrict__ w2t){
  __shared__ unsigned short tl[32][33];
  const int e = blockIdx.z;
  const int d0 = blockIdx.x*32, f0 = blockIdx.y*32;
  const int tx = threadIdx.x, ty = threadIdx.y;
  #pragma unroll
  for (int i=0;i<4;i++)
    tl[ty + i*8][tx] = f2b(w2[((long)(e*FF + f0 + ty + i*8))*D_MODEL + d0 + tx]);
  __syncthreads();
  #pragma unroll
  for (int i=0;i<4;i++)
    w2t[((long)e*D_MODEL + d0 + ty + i*8)*FF + f0 + tx] = tl[tx][ty + i*8];
}

// ---------------- GEMM1: Hg = silu(Xg @ w1e^T) * (Xg @ v1e^T) ----------------
// width-16 global_load_lds staging; XOR-swizzled LDS; XCD-aware block swizzle:
// xcd = b&7 owns a contiguous 9-mt stripe -> B-pair + 9 A-tiles stay L2-resident.
__global__ __launch_bounds__(256, 3) void gemm1_swiglu(
    const unsigned short* __restrict__ x,
    const unsigned short* __restrict__ w1,
    const unsigned short* __restrict__ v1,
    const int* __restrict__ perm,
    const int* __restrict__ tileExpert,
    unsigned short* __restrict__ Hg)
{
  const int b = blockIdx.x;                    // 0..1151
  const int xcd = b & 7, s = b >> 3;           // s: 0..143
  const int mt = xcd*9 + (s % 9);              // 9-mt stripe per XCD
  const int nt = s / 9;                        // 0..15
  int e = tileExpert[mt];
  if (e < 0) return;
  e &= 7;
  __shared__ alignas(16) unsigned short As [MT*BK];
  __shared__ alignas(16) unsigned short B1s[MT*BK];
  __shared__ alignas(16) unsigned short B2s[MT*BK];
  const int tid = threadIdx.x;
  const int lane = tid & 63;
  const int wr = ((tid >> 7) & 1) * 64;
  const int wc = ((tid >> 6) & 1) * 64;

  long aoff[4]; long boff[4]; int dstIdx[4];
  #pragma unroll
  for (int i=0;i<4;i++){
    int idx = tid + 256*i;
    int r = idx >> 3, c = idx & 7;
    int sc = c ^ (r & 7);                 // XOR swizzle (applied on global side)
    int tok = perm[mt*MT + r]; if (tok < 0 || tok >= NTOK) tok = 0;
    aoff[i] = (long)tok * D_MODEL + sc*8;
    boff[i] = ((long)e*FF + nt*MT + r) * D_MODEL + sc*8;
    dstIdx[i] = idx * 8;
  }
  f32x4 zero = {0.f,0.f,0.f,0.f};
  f32x4 acc1[4][4], acc2[4][4];
  #pragma unroll
  for (int i=0;i<4;i++)
    #pragma unroll
    for (int j=0;j<4;j++){ acc1[i][j] = zero; acc2[i][j] = zero; }

  for (int k0 = 0; k0 < D_MODEL; k0 += BK){
    __syncthreads();
    #pragma unroll
    for (int i=0;i<4;i++) gl2lds16(x  + aoff[i] + k0, &As [dstIdx[i]]);
    #pragma unroll
    for (int i=0;i<4;i++) gl2lds16(w1 + boff[i] + k0, &B1s[dstIdx[i]]);
    #pragma unroll
    for (int i=0;i<4;i++) gl2lds16(v1 + boff[i] + k0, &B2s[dstIdx[i]]);
    __syncthreads();
    #pragma unroll
    for (int kk = 0; kk < BK; kk += 32){
      const int q = (lane >> 4) + (kk >> 3);   // logical 8-elem chunk 0..7
      bf16x8 a[4], bb1[4], bb2[4];
      #pragma unroll
      for (int i=0;i<4;i++){
        int r = wr + i*16 + (lane & 15);
        a[i] = *reinterpret_cast<const bf16x8*>(&As[r*BK + ((q ^ (r&7))*8)]);
      }
      #pragma unroll
      for (int j=0;j<4;j++){
        int n = wc + j*16 + (lane & 15);
        int adr = n*BK + ((q ^ (n&7))*8);
        bb1[j] = *reinterpret_cast<const bf16x8*>(&B1s[adr]);
        bb2[j] = *reinterpret_cast<const bf16x8*>(&B2s[adr]);
      }
      #pragma unroll
      for (int i=0;i<4;i++)
        #pragma unroll
        for (int j=0;j<4;j++){
          acc1[i][j] = __builtin_amdgcn_mfma_f32_16x16x32_bf16(a[i], bb1[j], acc1[i][j], 0,0,0);
          acc2[i][j] = __builtin_amdgcn_mfma_f32_16x16x32_bf16(a[i], bb2[j], acc2[i][j], 0,0,0);
        }
    }
  }
  // epilogue: h = silu(g)*u, write bf16.  C/D layout: col=lane&15, row=quad*4+reg
  const int mrow0 = mt*MT + wr + ((lane >> 4) << 2);
  const int ncol0 = nt*MT + wc + (lane & 15);
  #pragma unroll
  for (int i=0;i<4;i++)
    #pragma unroll
    for (int j=0;j<4;j++)
      #pragma unroll
      for (int rr=0;rr<4;rr++){
        float g = acc1[i][j][rr];
        float u = acc2[i][j][rr];
        float h = (g / (1.0f + __expf(-g))) * u;
        Hg[(long)(mrow0 + i*16 + rr)*FF + (ncol0 + j*16)] = f2b(h);
      }
}

// ---------------- GEMM2: Yg(fp32) = Hg @ w2e  (B from transposed w2t) --------
// XCD swizzle: A-tile (Hg rows) reused 8x consecutively within an XCD.
__global__ __launch_bounds__(256, 3) void gemm2_kernel(
    const unsigned short* __restrict__ Hg,
    const unsigned short* __restrict__ w2t,   // [E][D][F] bf16
    const int* __restrict__ tileExpert,
    float* __restrict__ Yg)
{
  const int b = blockIdx.x;                    // 0..575
  const int xcd = b & 7, s = b >> 3;           // s: 0..71
  const int mt = xcd + 8*(s >> 3);             // 9 mts per XCD (stride 8)
  const int nt = s & 7;                        // 0..7
  int e = tileExpert[mt];
  if (e < 0) return;
  e &= 7;
  __shared__ alignas(16) unsigned short As[MT*BK];
  __shared__ alignas(16) unsigned short Bs[MT*BK];
  const int tid = threadIdx.x;
  const int lane = tid & 63;
  const int wr = ((tid >> 7) & 1) * 64;
  const int wc = ((tid >> 6) & 1) * 64;

  long aoff[4]; long boff[4]; int dstIdx[4];
  #pragma unroll
  for (int i=0;i<4;i++){
    int idx = tid + 256*i;
    int r = idx >> 3, c = idx & 7;
    int sc = c ^ (r & 7);
    aoff[i] = (long)(mt*MT + r) * FF + sc*8;
    boff[i] = ((long)e*D_MODEL + nt*MT + r) * FF + sc*8;
    dstIdx[i] = idx * 8;
  }
  f32x4 zero = {0.f,0.f,0.f,0.f};
  f32x4 acc[4][4];
  #pragma unroll
  for (int i=0;i<4;i++)
    #pragma unroll
    for (int j=0;j<4;j++) acc[i][j] = zero;

  for (int k0 = 0; k0 < FF; k0 += BK){
    __syncthreads();
    #pragma unroll
    for (int i=0;i<4;i++) gl2lds16(Hg  + aoff[i] + k0, &As[dstIdx[i]]);
    #pragma unroll
    for (int i=0;i<4;i++) gl2lds16(w2t + boff[i] + k0, &Bs[dstIdx[i]]);
    __syncthreads();
    #pragma unroll
    for (int kk = 0; kk < BK; kk += 32){
      const int q = (lane >> 4) + (kk >> 3);
      bf16x8 a[4], bb[4];
      #pragma unroll
      for (int i=0;i<4;i++){
        int r = wr + i*16 + (lane & 15);
        a[i] = *reinterpret_cast<const bf16x8*>(&As[r*BK + ((q ^ (r&7))*8)]);
      }
      #pragma unroll
      for (int j=0;j<4;j++){
        int n = wc + j*16 + (lane & 15);
        bb[j] = *reinterpret_cast<const bf16x8*>(&Bs[n*BK + ((q ^ (n&7))*8)]);
      }
      #pragma unroll
      for (int i=0;i<4;i++)
        #pragma unroll
        for (int j=0;j<4;j++)
          acc[i][j] = __builtin_amdgcn_mfma_f32_16x16x32_bf16(a[i], bb[j], acc[i][j], 0,0,0);
    }
  }
  const int mrow0 = mt*MT + wr + ((lane >> 4) << 2);
  const int ncol0 = nt*MT + wc + (lane & 15);
  #pragma unroll
  for (int i=0;i<4;i++)
    #pragma unroll
    for (int j=0;j<4;j++)
      #pragma unroll
      for (int rr=0;rr<4;rr++)
        Yg[(long)(mrow0 + i*16 + rr)*D_MODEL + (ncol0 + j*16)] = acc[i][j][rr];
}

// ---------------- combine: out[t] = w0*Yg[r0] + w1*Yg[r1]  (fp32) ------------
__global__ __launch_bounds__(256) void combine_kernel(
    const float* __restrict__ Yg, const float* __restrict__ topw,
    const int* __restrict__ rowOf, float* __restrict__ out)
{
  const int t = blockIdx.x;
  const int d = threadIdx.x * 4;
  const float wA = topw[2*t], wB = topw[2*t+1];
  long rA = rowOf[2*t], rB = rowOf[2*t+1];
  if (rA < 0 || rA >= MAXROWS) rA = 0;
  if (rB < 0 || rB >= MAXROWS) rB = 0;
  float4 a = *reinterpret_cast<const float4*>(Yg + rA*D_MODEL + d);
  float4 b = *reinterpret_cast<const float4*>(Yg + rB*D_MODEL + d);
  float4 o;
  o.x = wA*a.x + wB*b.x;
  o.y = wA*a.y + wB*b.y;
  o.z = wA*a.z + wB*b.z;
  o.w = wA*a.w + wB*b.w;
  *reinterpret_cast<float4*>(out + (long)t*D_MODEL + d) = o;
}

// ---------------- launch ----------------
extern "C" void kernel_launch(void* const* d_in, const int* in_sizes, int n_in,
                              void* d_out, int out_size, void* d_ws, size_t ws_size,
                              hipStream_t stream)
{
  const float* x  = (const float*)d_in[0];
  const float* w1 = (const float*)d_in[1];
  const float* v1 = (const float*)d_in[2];
  const float* w2 = (const float*)d_in[3];
  const float* rw = (const float*)d_in[4];
  float* out = (float*)d_out;
  (void)in_sizes; (void)n_in;

  // --- workspace layout + budget check ---
  size_t need = 0;
  auto count = [&](size_t b){ size_t r = need; need += (b + 255) & ~(size_t)255; return r; };
  size_t o_topw = count((size_t)NTOK*TOPK*sizeof(float));
  size_t o_tope = count((size_t)NTOK*TOPK*sizeof(int));
  size_t o_ctrl = count(64*sizeof(int));
  size_t o_seg  = count(16*sizeof(int));
  size_t o_te   = count(MAXTILES*sizeof(int));
  size_t o_perm = count(MAXROWS*sizeof(int));
  size_t o_rowOf= count((size_t)NTOK*TOPK*sizeof(int));
  size_t o_xb   = count((size_t)NTOK*D_MODEL*2);          // bf16 x
  size_t o_w1b  = count((size_t)NEXP*FF*D_MODEL*2);       // bf16 w1
  size_t o_v1b  = count((size_t)NEXP*FF*D_MODEL*2);       // bf16 v1
  size_t o_w2t  = count((size_t)NEXP*D_MODEL*FF*2);       // bf16 w2^T
  size_t o_Hg   = count((size_t)MAXROWS*FF*2);            // bf16 hidden
  size_t o_Yg   = count((size_t)MAXROWS*D_MODEL*sizeof(float)); // fp32 expert out

  if (ws_size < need){
    // diagnostic fallback: clean wrong-answer (absmax=max|ref|) instead of fault
    zero_out_kernel<<<(out_size+255)/256, 256, 0, stream>>>(out, out_size);
    return;
  }

  char* base = (char*)d_ws;
  float* topw      = (float*)(base + o_topw);
  int*   tope      = (int*)  (base + o_tope);
  int*   ctrl      = (int*)  (base + o_ctrl);   // counts=ctrl[0..7], fill=ctrl[8..15]
  int*   segStart  = (int*)  (base + o_seg);
  int*   tileExpert= (int*)  (base + o_te);
  int*   perm      = (int*)  (base + o_perm);
  int*   rowOf     = (int*)  (base + o_rowOf);
  unsigned short* xb  = (unsigned short*)(base + o_xb);
  unsigned short* w1b = (unsigned short*)(base + o_w1b);
  unsigned short* v1b = (unsigned short*)(base + o_v1b);
  unsigned short* w2t = (unsigned short*)(base + o_w2t);
  unsigned short* Hg  = (unsigned short*)(base + o_Hg);
  float*          Yg  = (float*)         (base + o_Yg);

  const long nx4 = (long)NTOK*D_MODEL/4;        // 1M float4s
  const long nw4 = (long)NEXP*FF*D_MODEL/4;     // 4M float4s

  init_kernel     <<<(MAXROWS+255)/256, 256, 0, stream>>>(perm, ctrl);
  router_kernel   <<<NTOK/4, 256, 0, stream>>>(x, rw, topw, tope, ctrl);
  partition_kernel<<<1, 64, 0, stream>>>(ctrl, segStart, tileExpert);
  scatter_kernel  <<<NTOK*TOPK/256, 256, 0, stream>>>(tope, segStart, ctrl+8, perm, rowOf);
  conv_kernel     <<<(nx4+255)/256, 256, 0, stream>>>(x,  xb,  nx4);
  conv_kernel     <<<(nw4+255)/256, 256, 0, stream>>>(w1, w1b, nw4);
  conv_kernel     <<<(nw4+255)/256, 256, 0, stream>>>(v1, v1b, nw4);
  transpose_w2    <<<dim3(D_MODEL/32, FF/32, NEXP), dim3(32,8), 0, stream>>>(w2, w2t);
  gemm1_swiglu    <<<MAXTILES*(FF/MT), 256, 0, stream>>>(xb, w1b, v1b, perm, tileExpert, Hg);
  gemm2_kernel    <<<MAXTILES*(D_MODEL/MT), 256, 0, stream>>>(Hg, w2t, tileExpert, Yg);
  combine_kernel  <<<NTOK, 256, 0, stream>>>(Yg, topw, rowOf, out);
}